// Round 1
// baseline (4784.851 us; speedup 1.0000x reference)
//
#include <hip/hip_runtime.h>

typedef unsigned short u16;
typedef __bf16 bf16_t;
typedef bf16_t bf16x8 __attribute__((ext_vector_type(8)));
typedef float f32x4 __attribute__((ext_vector_type(4)));

#define DEV static __device__ __forceinline__

DEV u16 f2bf(float f){ unsigned u = __float_as_uint(f); return (u16)((u + 0x7fffu + ((u>>16)&1u))>>16); }
DEV float bf2f(u16 b){ return __uint_as_float(((unsigned)b)<<16); }
DEV float sigf(float x){ return 1.0f/(1.0f+__expf(-x)); }
DEV float tanhf_(float x){ float e = __expf(2.0f*x); return 1.0f - 2.0f/(e+1.0f); }

union FragU { bf16x8 v; u16 u[8]; };

DEV void gload_lds16(const void* g, void* l){
  __builtin_amdgcn_global_load_lds((const __attribute__((address_space(1))) void*)g,
                                   (__attribute__((address_space(3))) void*)l, 16, 0, 0);
}

// Stage a [128 rows][32 k] bf16 weight tile into LDS.
// LDS layout: row n has 4 16B slots; physical slot = logical slot ^ ((n>>1)&3)  (bank swizzle).
// global_load_lds writes lane l's 16B at (wave-uniform base + l*16), so source addrs are pre-swizzled.
template<bool GATE>
DEV void stageW(const u16* Wbase, int ldw, int kcol, int hbase, u16* ldsW, int tid){
  int w = tid >> 6;
#pragma unroll
  for (int p = 0; p < 2; ++p){
    int flat = p*256 + tid;
    int n = flat >> 2, sp = flat & 3;
    int sl = sp ^ ((n>>1)&3);
    int j = GATE ? ((n>>5)*256 + hbase + (n&31)) : n;
    gload_lds16(Wbase + (size_t)j*ldw + kcol + sl*8, ldsW + (size_t)(p*256 + w*64)*8);
  }
}

// Read B-fragment for MFMA: lane holds B[k = 8*(lane>>4)+i][col = lane&15] = W[row n][k]
DEV bf16x8 readW(const u16* ldsW, int n, int l4){
  int sl = l4 ^ ((n>>1)&3);
  return *reinterpret_cast<const bf16x8*>(ldsW + n*32 + sl*8);
}

// ---------------- fused LSTM cell ----------------
// gates[s,b,j] = sum_k h[s,b,k]*Whh[s,j,k] + sum_k x[s,b,k]*Wih[s,j,k] + bias[s,j]
// then pointwise -> c (fp32), h_out (bf16).
// MODE 0: x fp32, KX=16 (padded Wih [S,1024,32]) ; MODE 1: x fp32, KX=4 ; MODE 2: x bf16 [S,B,256]
struct CellArgs {
  const u16* Whh; const u16* Wih; const u16* hA; const void* xA;
  const float* bias; float* c; u16* hOut; int t; int Tdim;
};

template<int MODE>
__global__ __launch_bounds__(256) void k_cell(CellArgs A){
  __shared__ u16 ldsW[128*32];
  int bid = blockIdx.x;
  int htile = bid & 7, s = (bid>>3) & 7, btile = bid >> 6;   // htile slowest-varying mod 8 => same-XCD weight sharing
  int tid = threadIdx.x, w = tid>>6, lane = tid&63, l15 = lane&15, l4 = lane>>4;
  int msub = w & 1, ng = w >> 1;           // wave: one M-subtile, gate-parity ng (nsubs q*2+ng)
  int hbase = htile*32;
  int brow0 = btile*32 + msub*16;

  f32x4 acc[4];
#pragma unroll
  for (int q=0;q<4;q++) acc[q] = (f32x4){0.f,0.f,0.f,0.f};

  const u16* WhhS = A.Whh + (size_t)s*1024*256;
  const u16* hS   = A.hA  + (size_t)s*256*256;

  // ---- h-part: K = 256 over Whh ----
  for (int ck = 0; ck < 8; ++ck){
    __syncthreads();
    stageW<true>(WhhS, 256, ck*32, hbase, ldsW, tid);
    bf16x8 af = *reinterpret_cast<const bf16x8*>(hS + (size_t)(brow0+l15)*256 + ck*32 + l4*8);
    __syncthreads();
#pragma unroll
    for (int q=0;q<4;q++){
      int n = (q*2+ng)*16 + l15;
      acc[q] = __builtin_amdgcn_mfma_f32_16x16x32_bf16(af, readW(ldsW,n,l4), acc[q], 0,0,0);
    }
  }

  // ---- x-part ----
  if (MODE == 2){
    const u16* WihS = A.Wih + (size_t)s*1024*256;
    const u16* xS   = (const u16*)A.xA + (size_t)s*256*256;
    for (int ck = 0; ck < 8; ++ck){
      __syncthreads();
      stageW<true>(WihS, 256, ck*32, hbase, ldsW, tid);
      bf16x8 af = *reinterpret_cast<const bf16x8*>(xS + (size_t)(brow0+l15)*256 + ck*32 + l4*8);
      __syncthreads();
#pragma unroll
      for (int q=0;q<4;q++){
        int n = (q*2+ng)*16 + l15;
        acc[q] = __builtin_amdgcn_mfma_f32_16x16x32_bf16(af, readW(ldsW,n,l4), acc[q], 0,0,0);
      }
    }
  } else {
    const u16* WihS = A.Wih + (size_t)s*1024*32;   // zero-padded to 32 cols
    __syncthreads();
    stageW<true>(WihS, 32, 0, hbase, ldsW, tid);
    FragU af;
#pragma unroll
    for (int e=0;e<8;e++) af.u[e] = 0;
    if (MODE == 0){
      if (l4 < 2){
        const float* xp = (const float*)A.xA + ((size_t)(s*256 + brow0 + l15)*A.Tdim + A.t)*16 + l4*8;
#pragma unroll
        for (int e=0;e<8;e++) af.u[e] = f2bf(xp[e]);
      }
    } else {
      if (l4 == 0){
        const float* xp = (const float*)A.xA + ((size_t)(s*256 + brow0 + l15)*A.Tdim + A.t)*4;
#pragma unroll
        for (int e=0;e<4;e++) af.u[e] = f2bf(xp[e]);
      }
    }
    __syncthreads();
#pragma unroll
    for (int q=0;q<4;q++){
      int n = (q*2+ng)*16 + l15;
      acc[q] = __builtin_amdgcn_mfma_f32_16x16x32_bf16(af.v, readW(ldsW,n,l4), acc[q], 0,0,0);
    }
  }

  // ---- pointwise epilogue: this wave holds all 4 gates for its (b,h) tile ----
  const float* bS = A.bias + s*1024;
  float* cS = A.c + (size_t)s*256*256;
  u16* hO = A.hOut + (size_t)s*256*256;
  int hcol = hbase + ng*16 + l15;
  float bi = bS[hcol], bff = bS[256+hcol], bg = bS[512+hcol], bo = bS[768+hcol];
#pragma unroll
  for (int r=0;r<4;r++){
    int brow = brow0 + l4*4 + r;
    size_t off = (size_t)brow*256 + hcol;
    float gi = acc[0][r] + bi;
    float gf = acc[1][r] + bff;
    float gg = acc[2][r] + bg;
    float go = acc[3][r] + bo;
    float cold = cS[off];
    float cnew = sigf(gf)*cold + sigf(gi)*tanhf_(gg);
    cS[off] = cnew;
    hO[off] = f2bf(sigf(go)*tanhf_(cnew));
  }
}

// ---------------- headers_in: hin = relu(win_h @ h1 + lev*win_lev) ----------------
struct HinArgs { const u16* winH; const float* winLev; const u16* h1; const float* lev; u16* hin; };

__global__ __launch_bounds__(256) void k_hin(HinArgs A){
  __shared__ u16 ldsW[128*32];
  int bid = blockIdx.x;                  // 8s x 8btile x 2ntile = 128
  int s = bid>>4, btile = (bid>>1)&7, ntile = bid&1;
  int tid = threadIdx.x, w = tid>>6, lane = tid&63, l15 = lane&15, l4 = lane>>4;
  int msub = w & 1, ng = w >> 1;
  int brow0 = btile*32 + msub*16;
  f32x4 acc[4];
#pragma unroll
  for (int q=0;q<4;q++) acc[q] = (f32x4){0.f,0.f,0.f,0.f};

  const u16* WS = A.winH + ((size_t)s*256 + ntile*128)*256;
  const u16* hS = A.h1 + (size_t)s*256*256;
  for (int ck = 0; ck < 8; ++ck){
    __syncthreads();
    stageW<false>(WS, 256, ck*32, 0, ldsW, tid);
    bf16x8 af = *reinterpret_cast<const bf16x8*>(hS + (size_t)(brow0+l15)*256 + ck*32 + l4*8);
    __syncthreads();
#pragma unroll
    for (int q=0;q<4;q++){
      int n = (ng*4+q)*16 + l15;
      acc[q] = __builtin_amdgcn_mfma_f32_16x16x32_bf16(af, readW(ldsW,n,l4), acc[q], 0,0,0);
    }
  }
  const float* wl = A.winLev + s*256 + ntile*128;
  const float* levS = A.lev + s*256;
  u16* out = A.hin + (size_t)s*256*256 + ntile*128;
#pragma unroll
  for (int q=0;q<4;q++){
    int m = (ng*4+q)*16 + l15;
    float wlev = wl[m];
#pragma unroll
    for (int r=0;r<4;r++){
      int b = brow0 + l4*4 + r;
      float v = acc[q][r] + levS[b]*wlev;
      out[(size_t)b*256 + m] = f2bf(fmaxf(v, 0.f));
    }
  }
}

// ---------------- graph conv + flow + lev update ----------------
// graphed[s,b,m] = sum_t adj[s,t] * (hin[t,b,:] . gT[m,:]) + gb[m]
// flow[s,b] = sum_m relu(graphed)*wout[s,m]; out[b,tg,s] = flow; lev += flow*fstd[s]
struct GfArgs { const u16* gT; const u16* hin; const float* gb; const float* wout;
                const float* adj; const float* fstd; float* lev; float* out; int tg; };

__global__ __launch_bounds__(256) void k_graphflow(GfArgs A){
  __shared__ float red[4][16];
  int bid = blockIdx.x;                  // 8s x 16btile
  int s = bid>>4, btile = bid&15;
  int tid = threadIdx.x, w = tid>>6, lane = tid&63, l15 = lane&15, l4 = lane>>4;
  int brow0 = btile*16;
  f32x4 acc[4];
#pragma unroll
  for (int q=0;q<4;q++) acc[q] = (f32x4){0.f,0.f,0.f,0.f};

  for (int ck = 0; ck < 8; ++ck){
    bf16x8 bfr[4];
#pragma unroll
    for (int q=0;q<4;q++){
      int n = (w*4+q)*16 + l15;
      bfr[q] = *reinterpret_cast<const bf16x8*>(A.gT + (size_t)n*256 + ck*32 + l4*8);
    }
    for (int t = 0; t < 8; ++t){
      float a = A.adj[s*8 + t];
      if (a == 0.f) continue;
      FragU af;
      af.v = *reinterpret_cast<const bf16x8*>(A.hin + ((size_t)t*256 + brow0 + l15)*256 + ck*32 + l4*8);
      if (a != 1.0f){
#pragma unroll
        for (int e=0;e<8;e++) af.u[e] = f2bf(bf2f(af.u[e])*a);
      }
#pragma unroll
      for (int q=0;q<4;q++)
        acc[q] = __builtin_amdgcn_mfma_f32_16x16x32_bf16(af.v, bfr[q], acc[q], 0,0,0);
    }
  }
  float part[4] = {0.f,0.f,0.f,0.f};
  const float* woS = A.wout + s*256;
#pragma unroll
  for (int q=0;q<4;q++){
    int m = (w*4+q)*16 + l15;
    float gbv = A.gb[m], wo = woS[m];
#pragma unroll
    for (int r=0;r<4;r++)
      part[r] += fmaxf(acc[q][r] + gbv, 0.f) * wo;
  }
#pragma unroll
  for (int d = 1; d < 16; d <<= 1){
#pragma unroll
    for (int r=0;r<4;r++) part[r] += __shfl_xor(part[r], d, 64);
  }
  if (l15 == 0){
#pragma unroll
    for (int r=0;r<4;r++) red[w][l4*4+r] = part[r];
  }
  __syncthreads();
  if (tid < 16){
    float flow = red[0][tid] + red[1][tid] + red[2][tid] + red[3][tid];
    int b = brow0 + tid;
    A.out[(size_t)b*720 + A.tg*8 + s] = flow;
    A.lev[s*256 + b] += flow * A.fstd[s];
  }
}

// ---------------- preamble conversion kernels ----------------
struct Cvt9Args { const float* s[9]; u16* d[9]; };
__global__ void k_cvt9(Cvt9Args A){
  size_t i = (size_t)blockIdx.x*256 + threadIdx.x;   // 9 x 2^21 elems
  int t = (int)(i >> 21); size_t r = i & 2097151u;
  A.d[t][r] = f2bf(A.s[t][r]);
}
struct Pad3Args { const float* s[3]; u16* d[3]; int kx[3]; };
__global__ void k_pad3(Pad3Args A){
  size_t i = (size_t)blockIdx.x*256 + threadIdx.x;   // 3 x 2^18
  int t = (int)(i >> 18); int r = (int)(i & 262143u);
  int row = r >> 5, col = r & 31;
  int kx = A.kx[t];
  A.d[t][r] = (col < kx) ? f2bf(A.s[t][(size_t)row*kx + col]) : (u16)0;
}
__global__ void k_win(const float* win, u16* winH, float* winLev){
  size_t i = (size_t)blockIdx.x*256 + threadIdx.x;   // 8*256*257
  if (i >= (size_t)8*256*257) return;
  int k = (int)(i % 257); size_t sm = i / 257;
  float v = win[i];
  if (k < 256) winH[sm*256 + k] = f2bf(v);
  else winLev[sm] = v;
}
__global__ void k_gt(const float* gW, u16* gT){
  int i = blockIdx.x*256 + threadIdx.x;              // 65536
  int h = i >> 8, k = i & 255;
  gT[(size_t)k*256 + h] = f2bf(gW[i]);               // gT[m][h] = gW[h][m]
}

// ---------------- host ----------------
extern "C" void kernel_launch(void* const* d_in, const int* in_sizes, int n_in,
                              void* d_out, int out_size, void* d_ws, size_t ws_size,
                              hipStream_t stream){
  const float* x_d    = (const float*)d_in[0];
  const float* x_f    = (const float*)d_in[1];
  const float* x_ff   = (const float*)d_in[2];
  const float* level0 = (const float*)d_in[3];
  const float* fstd   = (const float*)d_in[4];
  const float* adj    = (const float*)d_in[5];
  const float* W[18];
  for (int i=0;i<18;i++) W[i] = (const float*)d_in[6+i];
  const float* win  = (const float*)d_in[24];
  const float* wout = (const float*)d_in[25];
  const float* gW   = (const float*)d_in[26];
  const float* gb   = (const float*)d_in[27];
  float* out = (float*)d_out;

  char* base = (char*)d_ws;
  size_t off = 0;
  auto alloc = [&](size_t bytes)->void*{
    void* r = base + off;
    off += (bytes + 255) & ~(size_t)255;
    return r;
  };
  u16* wb[9]; for (int i=0;i<9;i++) wb[i] = (u16*)alloc((size_t)2097152*2);
  u16* wp[3]; for (int i=0;i<3;i++) wp[i] = (u16*)alloc((size_t)262144*2);
  u16* winH = (u16*)alloc((size_t)524288*2);
  u16* gT   = (u16*)alloc((size_t)65536*2);
  float* winLev = (float*)alloc((size_t)2048*4);
  float* c0 = (float*)alloc((size_t)524288*4);
  float* c1 = (float*)alloc((size_t)524288*4);
  u16* h0[2]; h0[0] = (u16*)alloc((size_t)524288*2); h0[1] = (u16*)alloc((size_t)524288*2);
  u16* h1[2]; h1[0] = (u16*)alloc((size_t)524288*2); h1[1] = (u16*)alloc((size_t)524288*2);
  u16* hin = (u16*)alloc((size_t)524288*2);
  float* lev = (float*)alloc((size_t)2048*4);

  // --- preamble: weight conversion + state init ---
  Cvt9Args c9;
  const float* c9s[9] = { W[1], W[3], W[4],  W[7], W[9], W[10],  W[13], W[15], W[16] };
  for (int i=0;i<9;i++){ c9.s[i] = c9s[i]; c9.d[i] = wb[i]; }
  k_cvt9<<<73728,256,0,stream>>>(c9);

  Pad3Args p3;
  const float* p3s[3] = { W[0], W[6], W[12] };
  int kx3[3] = {16,16,4};
  for (int i=0;i<3;i++){ p3.s[i]=p3s[i]; p3.d[i]=wp[i]; p3.kx[i]=kx3[i]; }
  k_pad3<<<3072,256,0,stream>>>(p3);

  k_win<<<2057,256,0,stream>>>(win, winH, winLev);
  k_gt<<<256,256,0,stream>>>(gW, gT);

  hipMemsetAsync(c0, 0, (size_t)524288*4, stream);
  hipMemsetAsync(c1, 0, (size_t)524288*4, stream);
  hipMemsetAsync(h0[0], 0, (size_t)524288*2, stream);
  hipMemsetAsync(h1[0], 0, (size_t)524288*2, stream);
  hipMemcpyAsync(lev, level0, (size_t)2048*4, hipMemcpyDeviceToDevice, stream);

  int p0 = 0, p1 = 0;

  // --- encode: 90 steps ---
  for (int t = 0; t < 90; ++t){
    CellArgs a0{wb[0], wp[0], h0[p0], (const void*)x_d, W[2], c0, h0[p0^1], t, 90};
    k_cell<0><<<512,256,0,stream>>>(a0); p0 ^= 1;
    CellArgs a1{wb[2], wb[1], h1[p1], (const void*)h0[p0], W[5], c1, h1[p1^1], 0, 0};
    k_cell<2><<<512,256,0,stream>>>(a1); p1 ^= 1;
  }
  // --- decode df: 14 steps ---
  for (int t = 0; t < 14; ++t){
    CellArgs a0{wb[3], wp[1], h0[p0], (const void*)x_f, W[8], c0, h0[p0^1], t, 14};
    k_cell<0><<<512,256,0,stream>>>(a0); p0 ^= 1;
    CellArgs a1{wb[5], wb[4], h1[p1], (const void*)h0[p0], W[11], c1, h1[p1^1], 0, 0};
    k_cell<2><<<512,256,0,stream>>>(a1); p1 ^= 1;
    HinArgs ha{winH, winLev, h1[p1], lev, hin};
    k_hin<<<128,256,0,stream>>>(ha);
    GfArgs ga{gT, hin, gb, wout, adj, fstd, lev, out, t};
    k_graphflow<<<128,256,0,stream>>>(ga);
  }
  // --- decode du: 76 steps ---
  for (int t = 0; t < 76; ++t){
    CellArgs a0{wb[6], wp[2], h0[p0], (const void*)x_ff, W[14], c0, h0[p0^1], t, 76};
    k_cell<1><<<512,256,0,stream>>>(a0); p0 ^= 1;
    CellArgs a1{wb[8], wb[7], h1[p1], (const void*)h0[p0], W[17], c1, h1[p1^1], 0, 0};
    k_cell<2><<<512,256,0,stream>>>(a1); p1 ^= 1;
    HinArgs ha{winH, winLev, h1[p1], lev, hin};
    k_hin<<<128,256,0,stream>>>(ha);
    GfArgs ga{gT, hin, gb, wout, adj, fstd, lev, out, 14 + t};
    k_graphflow<<<128,256,0,stream>>>(ga);
  }
}